// Round 1
// 72.843 us; speedup vs baseline: 1.0034x; 1.0034x over previous
//
#include <hip/hip_runtime.h>

// Problem constants (match reference)
#define NXG 2048
#define NYG 2048
// hx = hy = 1/2048 -> 1/h = 2048, 1/(2h) = 1024
__device__ __forceinline__ float inv_h()  { return 2048.0f; }
__device__ __forceinline__ float inv_2h() { return 1024.0f; }

#define BLOCK 256
#define GRID  1024   // 1024 * 256 threads = (2048/4 row-bands) * (2048/4 col-chunks)
#define NXCD  8

// Kernel 1: each thread processes a 4-ROW x float4 chunk: rows (4g..4g+3),
// cols j4..j4+3. The x-stencil needs rows 4g-1..4g+4 -> 6 float4 loads for
// 4 output rows (1.5 loads/row vs 2.0 in the row-pair version). Exactly one
// chunk per thread (no grid-stride loop). Block index is XCD-swizzled so
// band-adjacent blocks share an XCD L2 and halo rows hit cache instead of
// re-fetching from HBM.
__global__ __launch_bounds__(BLOCK) void
energy_partial_kernel(const float* __restrict__ phi, float* __restrict__ partial) {
    // Dispatch slot s round-robins to XCD s%8; remap so each XCD owns a
    // contiguous run of 128 consecutive work chunks (bijective: 1024%8==0).
    const int slot = blockIdx.x;
    const int wg   = (slot & (NXCD - 1)) * (GRID / NXCD) + (slot >> 3);
    const int c    = wg * BLOCK + threadIdx.x;

    const int g  = c >> 9;            // row-band index 0..511
    const int j4 = (c & 511) << 2;    // starting y index of this chunk
    const int r0 = 4 * g;             // first row of band

    const int rm = (g > 0)   ? r0 - 1 : 0;        // clamp top halo
    const int rp = (g < 511) ? r0 + 4 : NXG - 1;  // clamp bottom halo
    const float sx0 = (r0 == 0)  ? inv_h() : inv_2h();  // row 4g
    const float sx3 = (g == 511) ? inv_h() : inv_2h();  // row 4g+3

    const float* rowm = phi + (size_t)rm * NYG;
    const float* row0 = phi + (size_t)r0 * NYG;
    const float* row1 = row0 + NYG;
    const float* row2 = row1 + NYG;
    const float* row3 = row2 + NYG;
    const float* rowp = phi + (size_t)rp * NYG;

    const float4 a  = *(const float4*)(rowm + j4);  // halo above
    const float4 b0 = *(const float4*)(row0 + j4);
    const float4 b1 = *(const float4*)(row1 + j4);
    const float4 b2 = *(const float4*)(row2 + j4);
    const float4 b3 = *(const float4*)(row3 + j4);
    const float4 d  = *(const float4*)(rowp + j4);  // halo below

    float acc = 0.0f;

    // x-direction velocities: rows 4g+1, 4g+2 are always interior.
    {
        float v;
        v = (b1.x - a.x) * sx0;      acc = fmaf(v, v, acc);
        v = (b1.y - a.y) * sx0;      acc = fmaf(v, v, acc);
        v = (b1.z - a.z) * sx0;      acc = fmaf(v, v, acc);
        v = (b1.w - a.w) * sx0;      acc = fmaf(v, v, acc);
        v = (b2.x - b0.x) * inv_2h(); acc = fmaf(v, v, acc);
        v = (b2.y - b0.y) * inv_2h(); acc = fmaf(v, v, acc);
        v = (b2.z - b0.z) * inv_2h(); acc = fmaf(v, v, acc);
        v = (b2.w - b0.w) * inv_2h(); acc = fmaf(v, v, acc);
        v = (b3.x - b1.x) * inv_2h(); acc = fmaf(v, v, acc);
        v = (b3.y - b1.y) * inv_2h(); acc = fmaf(v, v, acc);
        v = (b3.z - b1.z) * inv_2h(); acc = fmaf(v, v, acc);
        v = (b3.w - b1.w) * inv_2h(); acc = fmaf(v, v, acc);
        v = (d.x - b2.x) * sx3;      acc = fmaf(v, v, acc);
        v = (d.y - b2.y) * sx3;      acc = fmaf(v, v, acc);
        v = (d.z - b2.z) * sx3;      acc = fmaf(v, v, acc);
        v = (d.w - b2.w) * sx3;      acc = fmaf(v, v, acc);
    }

    // y-direction velocities: per center row, from its own float4 plus
    // edge scalars at j4-1 / j4+4 (same cache lines as neighbors' float4s).
    const float4 rows[4] = { b0, b1, b2, b3 };
    const float* rptr[4] = { row0, row1, row2, row3 };
    #pragma unroll
    for (int r = 0; r < 4; ++r) {
        const float4 v4 = rows[r];
        float v;
        if (j4 == 0) {
            v = (v4.y - v4.x) * inv_h();
        } else {
            v = (v4.y - rptr[r][j4 - 1]) * inv_2h();
        }
        acc = fmaf(v, v, acc);
        v = (v4.z - v4.x) * inv_2h(); acc = fmaf(v, v, acc);
        v = (v4.w - v4.y) * inv_2h(); acc = fmaf(v, v, acc);
        if (j4 + 4 == NYG) {
            v = (v4.w - v4.z) * inv_h();
        } else {
            v = (rptr[r][j4 + 4] - v4.z) * inv_2h();
        }
        acc = fmaf(v, v, acc);
    }

    // wave (64-lane) shuffle reduction
    #pragma unroll
    for (int off = 32; off > 0; off >>= 1)
        acc += __shfl_down(acc, off, 64);

    __shared__ float smem[BLOCK / 64];
    const int lane = threadIdx.x & 63;
    const int wave = threadIdx.x >> 6;
    if (lane == 0) smem[wave] = acc;
    __syncthreads();
    if (threadIdx.x == 0) {
        float s = 0.0f;
        #pragma unroll
        for (int w = 0; w < BLOCK / 64; ++w) s += smem[w];
        partial[blockIdx.x] = s;
    }
}

// Kernel 2: single block reduces GRID partials, writes 0.5 * sum.
__global__ __launch_bounds__(BLOCK) void
energy_finalize_kernel(const float* __restrict__ partial, float* __restrict__ out) {
    float acc = 0.0f;
    for (int idx = threadIdx.x; idx < GRID; idx += BLOCK)
        acc += partial[idx];

    #pragma unroll
    for (int off = 32; off > 0; off >>= 1)
        acc += __shfl_down(acc, off, 64);

    __shared__ float smem[BLOCK / 64];
    const int lane = threadIdx.x & 63;
    const int wave = threadIdx.x >> 6;
    if (lane == 0) smem[wave] = acc;
    __syncthreads();
    if (threadIdx.x == 0) {
        float s = 0.0f;
        #pragma unroll
        for (int w = 0; w < BLOCK / 64; ++w) s += smem[w];
        out[0] = 0.5f * s;
    }
}

extern "C" void kernel_launch(void* const* d_in, const int* in_sizes, int n_in,
                              void* d_out, int out_size, void* d_ws, size_t ws_size,
                              hipStream_t stream) {
    // d_in[0] = pos (unused by the reference), d_in[1] = potential_field [2048*2048] f32
    const float* phi = (const float*)d_in[1];
    float* out = (float*)d_out;
    float* partial = (float*)d_ws;  // GRID floats of scratch

    energy_partial_kernel<<<GRID, BLOCK, 0, stream>>>(phi, partial);
    energy_finalize_kernel<<<1, BLOCK, 0, stream>>>(partial, out);
}